// Round 1
// baseline (109.920 us; speedup 1.0000x reference)
//
#include <hip/hip_runtime.h>

// CRPS loss: out = mean(|y_pred - y|) - sum_{i,k,l}|x[i,k]-x[i,l]| / (N*2*M^2)
// N=4096 rows, M=256 ensemble. Strategy: one block (256 thr) per row, row in
// LDS, brute-force O(M^2) pairwise term with float4 LDS reads (VALU-bound,
// ~6.8us floor), block reduce, one atomicAdd of pre-scaled partial per block.

constexpr int N_ROWS = 4096;
constexpr int M_COLS = 256;

__global__ __launch_bounds__(256)
void crps_kernel(const float* __restrict__ y_pred,
                 const float* __restrict__ y,
                 float* __restrict__ out) {
    __shared__ __align__(16) float row[M_COLS];
    __shared__ float wsum[4];

    const int i = blockIdx.x;
    const int k = threadIdx.x;

    const float xk = y_pred[i * M_COLS + k];
    row[k] = xk;
    const float yi = y[i];   // uniform per block -> scalar load
    __syncthreads();

    // Pairwise spread term for this thread's x_k: sum_l |x_k - row[l]|
    float mix = 0.0f;
    const float4* row4 = reinterpret_cast<const float4*>(row);
    #pragma unroll 8
    for (int l4 = 0; l4 < M_COLS / 4; ++l4) {
        const float4 v = row4[l4];
        mix += fabsf(xk - v.x);
        mix += fabsf(xk - v.y);
        mix += fabsf(xk - v.z);
        mix += fabsf(xk - v.w);
    }

    const float mae = fabsf(xk - yi);

    // Pre-scale so the global accumulation is just a sum.
    constexpr float mae_scale = 1.0f / ((float)N_ROWS * (float)M_COLS);
    constexpr float mix_scale = 1.0f / (2.0f * (float)N_ROWS * (float)M_COLS * (float)M_COLS);
    float part = mae * mae_scale - mix * mix_scale;

    // Wave-64 shuffle reduction
    #pragma unroll
    for (int off = 32; off > 0; off >>= 1)
        part += __shfl_down(part, off, 64);

    if ((k & 63) == 0) wsum[k >> 6] = part;
    __syncthreads();
    if (k == 0) {
        atomicAdd(out, wsum[0] + wsum[1] + wsum[2] + wsum[3]);
    }
}

extern "C" void kernel_launch(void* const* d_in, const int* in_sizes, int n_in,
                              void* d_out, int out_size, void* d_ws, size_t ws_size,
                              hipStream_t stream) {
    const float* y_pred = (const float*)d_in[0];
    const float* y      = (const float*)d_in[1];
    float* out          = (float*)d_out;

    // d_out is re-poisoned to 0xAA before every timed launch; zero it on-stream
    // (memset nodes are graph-capture safe).
    hipMemsetAsync(out, 0, sizeof(float), stream);

    crps_kernel<<<N_ROWS, 256, 0, stream>>>(y_pred, y, out);
}

// Round 2
// 76.327 us; speedup vs baseline: 1.4401x; 1.4401x over previous
//
#include <hip/hip_runtime.h>

// CRPS loss: out = mean(|y_pred - y|) - sum_{i,k,l}|x[i,k]-x[i,l]| / (N*2*M^2)
// N=4096 rows, M=256 ensemble.
//
// R1 post-mortem: 57.8us, VALUBusy 23.6%, VGPR=20 -> ds_read latency exposed,
// only 8 VALU ops per ds_read_b128. Fix: one WAVE per row, each lane owns 4
// k-values in registers; each broadcast float4 LDS read now feeds 32 VALU ops
// across 4 independent accumulators. 4x fewer LDS instrs, 4x the ILP.

constexpr int N_ROWS = 4096;
constexpr int M_COLS = 256;
constexpr int ROWS_PER_BLOCK = 4;   // 4 waves x 1 row each

__global__ __launch_bounds__(256)
void crps_kernel(const float* __restrict__ y_pred,
                 const float* __restrict__ y,
                 float* __restrict__ out) {
    __shared__ __align__(16) float4 rows[ROWS_PER_BLOCK][M_COLS / 4];
    __shared__ float wsum[ROWS_PER_BLOCK];

    const int wave = threadIdx.x >> 6;       // 0..3 -> which row of this block
    const int lane = threadIdx.x & 63;
    const int row  = blockIdx.x * ROWS_PER_BLOCK + wave;

    // Each lane loads its 4 owned k-values (elements 4*lane .. 4*lane+3),
    // keeps them in registers AND stages the row in LDS for the l-loop.
    const float4* gp = reinterpret_cast<const float4*>(y_pred + row * M_COLS);
    const float4 xk = gp[lane];
    rows[wave][lane] = xk;
    const float yi = y[row];                 // wave-uniform -> scalar load
    __syncthreads();

    // Pairwise term: 4 independent accumulators (one per owned k).
    float m0 = 0.0f, m1 = 0.0f, m2 = 0.0f, m3 = 0.0f;
    const float4* r4 = rows[wave];
    #pragma unroll 8
    for (int l = 0; l < M_COLS / 4; ++l) {
        const float4 v = r4[l];              // wave-uniform broadcast read
        m0 += fabsf(xk.x - v.x) + fabsf(xk.x - v.y) + fabsf(xk.x - v.z) + fabsf(xk.x - v.w);
        m1 += fabsf(xk.y - v.x) + fabsf(xk.y - v.y) + fabsf(xk.y - v.z) + fabsf(xk.y - v.w);
        m2 += fabsf(xk.z - v.x) + fabsf(xk.z - v.y) + fabsf(xk.z - v.z) + fabsf(xk.z - v.w);
        m3 += fabsf(xk.w - v.x) + fabsf(xk.w - v.y) + fabsf(xk.w - v.z) + fabsf(xk.w - v.w);
    }
    const float mix = (m0 + m1) + (m2 + m3);

    const float mae = fabsf(xk.x - yi) + fabsf(xk.y - yi)
                    + fabsf(xk.z - yi) + fabsf(xk.w - yi);

    // Pre-scale so global accumulation is a plain sum.
    constexpr float mae_scale = 1.0f / ((float)N_ROWS * (float)M_COLS);
    constexpr float mix_scale = 1.0f / (2.0f * (float)N_ROWS * (float)M_COLS * (float)M_COLS);
    float part = mae * mae_scale - mix * mix_scale;

    // Wave-64 shuffle reduction
    #pragma unroll
    for (int off = 32; off > 0; off >>= 1)
        part += __shfl_down(part, off, 64);

    if (lane == 0) wsum[wave] = part;
    __syncthreads();
    if (threadIdx.x == 0) {
        atomicAdd(out, (wsum[0] + wsum[1]) + (wsum[2] + wsum[3]));
    }
}

extern "C" void kernel_launch(void* const* d_in, const int* in_sizes, int n_in,
                              void* d_out, int out_size, void* d_ws, size_t ws_size,
                              hipStream_t stream) {
    const float* y_pred = (const float*)d_in[0];
    const float* y      = (const float*)d_in[1];
    float* out          = (float*)d_out;

    // d_out is re-poisoned to 0xAA before every timed launch; zero it on-stream.
    hipMemsetAsync(out, 0, sizeof(float), stream);

    crps_kernel<<<N_ROWS / ROWS_PER_BLOCK, 256, 0, stream>>>(y_pred, y, out);
}

// Round 3
// 74.299 us; speedup vs baseline: 1.4794x; 1.0273x over previous
//
#include <hip/hip_runtime.h>

// CRPS loss: out = mean(|y_pred - y|) - sum_{i,k,l}|x[i,k]-x[i,l]| / (N*2*M^2)
// N=4096 rows, M=256 ensemble.
//
// R2 post-mortem: kernel ~24us (bench 76.3 = 40.6us harness ws-poison fill +
// ~11us restore/launch + kernel). VALU floor is 6.8us. This round:
//  - 2 rows per wave, split by half-wave; each lane owns 8 k-values in regs.
//    One ds_read_b128 (2-way addr = free) feeds 64 VALU instrs (ratio 64:1).
//  - explicit prefetch double-buffer in the l-loop.
//  - no pre-loop __syncthreads: each half-wave reads only LDS it wrote itself.
//  - no same-address atomics: block partials -> d_ws, tiny kernel2 reduces 512
//    floats and plain-stores d_out (memset node dropped too).

constexpr int N_ROWS = 4096;
constexpr int M_COLS = 256;
constexpr int ROWS_PER_BLOCK = 8;                 // 4 waves x 2 rows
constexpr int NUM_BLOCKS = N_ROWS / ROWS_PER_BLOCK;  // 512

__global__ __launch_bounds__(256)
void crps_partial(const float* __restrict__ y_pred,
                  const float* __restrict__ y,
                  float* __restrict__ partial) {
    // +1 float4 pad per row: staggers the two half-wave broadcast addresses
    // across banks (2-way would be free anyway; this makes it unambiguous).
    __shared__ __align__(16) float4 rows[ROWS_PER_BLOCK][M_COLS / 4 + 1];
    __shared__ float wsum[4];

    const int wave = threadIdx.x >> 6;            // 0..3
    const int lane = threadIdx.x & 63;
    const int half = lane >> 5;                   // 0 or 1
    const int ll   = lane & 31;                   // lane within half-wave
    const int lrow = wave * 2 + half;             // local row 0..7
    const int row  = blockIdx.x * ROWS_PER_BLOCK + lrow;

    // Lane owns 8 consecutive floats (k = 8*ll .. 8*ll+7) of its row:
    // keep in registers AND stage into LDS for the l-loop broadcast reads.
    const float4* gp = reinterpret_cast<const float4*>(y_pred + row * M_COLS);
    const float4 xa = gp[2 * ll];
    const float4 xb = gp[2 * ll + 1];
    rows[lrow][2 * ll]     = xa;
    rows[lrow][2 * ll + 1] = xb;
    const float yi = y[row];

    float xo[8] = {xa.x, xa.y, xa.z, xa.w, xb.x, xb.y, xb.z, xb.w};
    float m[8]  = {0, 0, 0, 0, 0, 0, 0, 0};

    // NOTE: no __syncthreads needed — this half-wave reads only rows[lrow],
    // which it wrote itself; same-wave DS ordering (lgkmcnt) suffices.
    const float4* r4 = rows[lrow];

    auto acc = [&](const float4 v) {
        #pragma unroll
        for (int j = 0; j < 8; ++j) {
            m[j] += fabsf(xo[j] - v.x) + fabsf(xo[j] - v.y)
                  + fabsf(xo[j] - v.z) + fabsf(xo[j] - v.w);
        }
    };

    // Software-pipelined l-loop: next float4 in flight under 128cy of VALU.
    float4 cur = r4[0];
    #pragma unroll 4
    for (int l = 0; l < M_COLS / 4 - 1; ++l) {
        const float4 nxt = r4[l + 1];
        acc(cur);
        cur = nxt;
    }
    acc(cur);

    float mix = 0.0f, mae = 0.0f;
    #pragma unroll
    for (int j = 0; j < 8; ++j) {
        mix += m[j];
        mae += fabsf(xo[j] - yi);
    }

    constexpr float mae_scale = 1.0f / ((float)N_ROWS * (float)M_COLS);
    constexpr float mix_scale = 1.0f / (2.0f * (float)N_ROWS * (float)M_COLS * (float)M_COLS);
    float part = mae * mae_scale - mix * mix_scale;

    // Wave-64 shuffle reduction (covers both rows of this wave).
    #pragma unroll
    for (int off = 32; off > 0; off >>= 1)
        part += __shfl_down(part, off, 64);

    if (lane == 0) wsum[wave] = part;
    __syncthreads();
    if (threadIdx.x == 0)
        partial[blockIdx.x] = (wsum[0] + wsum[1]) + (wsum[2] + wsum[3]);
}

__global__ __launch_bounds__(512)
void crps_final(const float* __restrict__ partial, float* __restrict__ out) {
    __shared__ float wsum[8];
    const int t = threadIdx.x;
    float v = partial[t];                         // 512 partials, 1 per thread
    #pragma unroll
    for (int off = 32; off > 0; off >>= 1)
        v += __shfl_down(v, off, 64);
    if ((t & 63) == 0) wsum[t >> 6] = v;
    __syncthreads();
    if (t == 0) {
        float s = 0.0f;
        #pragma unroll
        for (int i = 0; i < 8; ++i) s += wsum[i];
        *out = s;                                 // plain store, no memset needed
    }
}

extern "C" void kernel_launch(void* const* d_in, const int* in_sizes, int n_in,
                              void* d_out, int out_size, void* d_ws, size_t ws_size,
                              hipStream_t stream) {
    const float* y_pred = (const float*)d_in[0];
    const float* y      = (const float*)d_in[1];
    float* out          = (float*)d_out;
    float* ws           = (float*)d_ws;           // 512 floats used

    crps_partial<<<NUM_BLOCKS, 256, 0, stream>>>(y_pred, y, ws);
    crps_final<<<1, 512, 0, stream>>>(ws, out);
}

// Round 4
// 65.304 us; speedup vs baseline: 1.6832x; 1.1377x over previous
//
#include <hip/hip_runtime.h>

// CRPS loss: out = mean(|y_pred - y|) - sum_{i,k,l}|x[i,k]-x[i,l]| / (N*2*M^2)
// N=4096 rows, M=256 ensemble.
//
// R3 post-mortem: R2 (32 VALU/ds_read) and R3 (64 VALU/ds_read) both ~22us ->
// not DS-bound; VALU-ISSUE bound at the emitted op count. R1 counters imply
// ~4 VALU instrs/pair (sub + and(abs) + add + overhead): the compiler is NOT
// folding fabsf into the VOP3 |src| modifier. R4: force p=2 with inline asm
// (v_sub + v_add_f32 m, m, |t|), and go to 4 waves/SIMD (1 row/wave, 1024
// blocks) for latency hiding. VALU floor: 268.4M pairs * 2 instr * 2cy / 64
// lanes / 1024 SIMDs = 16384 cy/SIMD = 6.8us.

constexpr int N_ROWS = 4096;
constexpr int M_COLS = 256;
constexpr int ROWS_PER_BLOCK = 4;                    // 4 waves x 1 row each
constexpr int NUM_BLOCKS = N_ROWS / ROWS_PER_BLOCK;  // 1024

// m += |a - b| as exactly 2 VALU instrs: v_sub + v_add with abs modifier.
__device__ __forceinline__ void abs_acc(float& m, float a, float b) {
    float t = a - b;
    asm("v_add_f32 %0, %0, |%1|" : "+v"(m) : "v"(t));
}

__global__ __launch_bounds__(256)
void crps_partial(const float* __restrict__ y_pred,
                  const float* __restrict__ y,
                  float* __restrict__ partial) {
    __shared__ __align__(16) float4 rows[ROWS_PER_BLOCK][M_COLS / 4];
    __shared__ float wsum[ROWS_PER_BLOCK];

    const int wave = threadIdx.x >> 6;               // 0..3 -> row of block
    const int lane = threadIdx.x & 63;
    const int row  = blockIdx.x * ROWS_PER_BLOCK + wave;

    // Lane owns 4 consecutive k-values; keep in regs AND stage row in LDS.
    const float4* gp = reinterpret_cast<const float4*>(y_pred + row * M_COLS);
    const float4 xk = gp[lane];
    rows[wave][lane] = xk;
    const float yi = y[row];                         // wave-uniform

    const float xo[4] = {xk.x, xk.y, xk.z, xk.w};
    float m[4] = {0, 0, 0, 0};

    // No barrier needed: this wave reads only rows[wave], written entirely by
    // itself; same-wave DS ops complete in order (relied on in R3, passed).
    const float4* r4 = rows[wave];

    auto acc4 = [&](const float4 v) {
        #pragma unroll
        for (int j = 0; j < 4; ++j) {
            abs_acc(m[j], xo[j], v.x);
            abs_acc(m[j], xo[j], v.y);
            abs_acc(m[j], xo[j], v.z);
            abs_acc(m[j], xo[j], v.w);
        }
    };

    // Software-pipelined broadcast l-loop.
    float4 cur = r4[0];
    #pragma unroll 4
    for (int l = 0; l < M_COLS / 4 - 1; ++l) {
        const float4 nxt = r4[l + 1];
        acc4(cur);
        cur = nxt;
    }
    acc4(cur);

    const float mix = (m[0] + m[1]) + (m[2] + m[3]);
    const float mae = fabsf(xo[0] - yi) + fabsf(xo[1] - yi)
                    + fabsf(xo[2] - yi) + fabsf(xo[3] - yi);

    constexpr float mae_scale = 1.0f / ((float)N_ROWS * (float)M_COLS);
    constexpr float mix_scale = 1.0f / (2.0f * (float)N_ROWS * (float)M_COLS * (float)M_COLS);
    float part = mae * mae_scale - mix * mix_scale;

    // Wave-64 shuffle reduction (one row per wave).
    #pragma unroll
    for (int off = 32; off > 0; off >>= 1)
        part += __shfl_down(part, off, 64);

    if (lane == 0) wsum[wave] = part;
    __syncthreads();
    if (threadIdx.x == 0)
        partial[blockIdx.x] = (wsum[0] + wsum[1]) + (wsum[2] + wsum[3]);
}

__global__ __launch_bounds__(256)
void crps_final(const float* __restrict__ partial, float* __restrict__ out) {
    __shared__ float wsum[4];
    const int t = threadIdx.x;
    // 1024 partials: each thread sums 4 via one float4 load.
    const float4 v4 = reinterpret_cast<const float4*>(partial)[t];
    float v = (v4.x + v4.y) + (v4.z + v4.w);
    #pragma unroll
    for (int off = 32; off > 0; off >>= 1)
        v += __shfl_down(v, off, 64);
    if ((t & 63) == 0) wsum[t >> 6] = v;
    __syncthreads();
    if (t == 0)
        *out = (wsum[0] + wsum[1]) + (wsum[2] + wsum[3]);
}

extern "C" void kernel_launch(void* const* d_in, const int* in_sizes, int n_in,
                              void* d_out, int out_size, void* d_ws, size_t ws_size,
                              hipStream_t stream) {
    const float* y_pred = (const float*)d_in[0];
    const float* y      = (const float*)d_in[1];
    float* out          = (float*)d_out;
    float* ws           = (float*)d_ws;              // 1024 floats used

    crps_partial<<<NUM_BLOCKS, 256, 0, stream>>>(y_pred, y, ws);
    crps_final<<<1, 256, 0, stream>>>(ws, out);
}